// Round 6
// baseline (747.841 us; speedup 1.0000x reference)
//
#include <hip/hip_runtime.h>
#include <cstdint>
#include <cstddef>

// Problem constants (fixed by reference)
#define N_SEQ 64
#define T_LEN 256
#define VOCAB 32000
#define EDIM  256
#define KS    128          // hidden states
#define KK    16384        // KS*KS
#define MROWS 16384        // padded (t,n) rows for GEMM (real: 255*64 = 16320)
#define MREAL 16320
#define GPART 16           // srow partial groups (by-split in gemm grid)

typedef short  short8  __attribute__((ext_vector_type(8)));
typedef float  floatx4 __attribute__((ext_vector_type(4)));
typedef float  floatx2 __attribute__((ext_vector_type(2)));

// lgkm-only barrier: does NOT drain vmcnt, so global prefetches stay in
// flight across the barrier (CK block_sync_lds pattern).
#define LGKM_BARRIER() asm volatile("s_waitcnt lgkmcnt(0)\n\ts_barrier" ::: "memory")

static __device__ __forceinline__ unsigned short f2bf(float f) {
  unsigned u = __float_as_uint(f);
  u += 0x7fffu + ((u >> 16) & 1u);          // RNE
  return (unsigned short)(u >> 16);
}

static __device__ __forceinline__ float4 cvt4_fp8(unsigned w) {
  float4 r;
#if __has_builtin(__builtin_amdgcn_cvt_pk_f32_fp8)
  floatx2 lo = __builtin_amdgcn_cvt_pk_f32_fp8((int)w, false);
  floatx2 hi = __builtin_amdgcn_cvt_pk_f32_fp8((int)w, true);
  r.x = lo[0]; r.y = lo[1]; r.z = hi[0]; r.w = hi[1];
#else
  r.x = __builtin_amdgcn_cvt_f32_fp8((int)w, 0);
  r.y = __builtin_amdgcn_cvt_f32_fp8((int)w, 1);
  r.z = __builtin_amdgcn_cvt_f32_fp8((int)w, 2);
  r.w = __builtin_amdgcn_cvt_f32_fp8((int)w, 3);
#endif
  return r;
}

static __device__ __forceinline__ void gl_lds16(const void* gptr, void* lptr) {
  // async global->LDS, 16B per lane; LDS dest = wave-uniform base + lane*16
  __builtin_amdgcn_global_load_lds(
      (const __attribute__((address_space(1))) void*)gptr,
      (__attribute__((address_space(3))) void*)lptr, 16, 0, 0);
}

// ---------------- start-distribution log_softmax -------------------------
__global__ __launch_bounds__(128) void k_prep(const float* sw, const float* sb, float* pre0) {
  __shared__ float vals[KS];
  __shared__ float MM, LS;
  int tid = threadIdx.x;
  float v = sw[tid] + sb[tid];
  vals[tid] = v;
  __syncthreads();
  if (tid == 0) { float m = vals[0]; for (int i = 1; i < KS; ++i) m = fmaxf(m, vals[i]); MM = m; }
  __syncthreads();
  float e = __expf(v - MM);
  vals[tid] = e;
  __syncthreads();
  if (tid == 0) { float s = 0.f; for (int i = 0; i < KS; ++i) s += vals[i]; LS = MM + __logf(s); }
  __syncthreads();
  pre0[tid] = v - LS;
}

// ------- trans_w fp32 -> bf16, ROW-PERMUTED row'=(j)*128+(i), k-SWIZZLED -
// 16B k-chunk c within each 128B slice stored at c ^ (row&7) so that the
// GEMM's fixed-layout global_load_lds tile ends up bank-conflict-free.
__global__ __launch_bounds__(256) void k_transcvt(const float* tw, unsigned short* tb) {
  int idx = blockIdx.x * 256 + threadIdx.x;          // over float4 groups
  if (idx >= (KK * EDIM) / 4) return;
  int row = idx >> 6, e4 = idx & 63;
  int rowp = ((row & 127) << 7) | (row >> 7);
  int e4s = (e4 & 0x31) | (((((e4 >> 1) & 7) ^ (rowp & 7))) << 1);
  float4 v = *(const float4*)&tw[(size_t)idx * 4];
  unsigned h0 = f2bf(v.x), h1 = f2bf(v.y), h2 = f2bf(v.z), h3 = f2bf(v.w);
  uint2 o; o.x = h0 | (h1 << 16); o.y = h2 | (h3 << 16);
  *(uint2*)&tb[(size_t)rowp * EDIM + e4s * 4] = o;
}

// ------- gather token embeddings -> bf16 rows m = t*64+n, k-SWIZZLED -----
__global__ __launch_bounds__(256) void k_embed(const int* x, const float* ew, unsigned short* exb) {
  int m = blockIdx.x, e = threadIdx.x;
  int t = m >> 6, n = m & 63;
  float v = 0.f;
  if (m < MREAL) { int tok = x[n * T_LEN + t]; v = ew[(size_t)tok * EDIM + e]; }
  int es = (e & 0xC7) | ((((e >> 3) & 7) ^ (m & 7)) << 3);
  exb[(size_t)m * EDIM + es] = f2bf(v);
}

// ---------------- emission logits C[k][v] = ecl[k] . emit_w[v] -----------
__global__ __launch_bounds__(256) void k_emitlogits(const float* ecl, const float* emw, float* C) {
  int v0 = blockIdx.x * 64, k0 = blockIdx.y * 64;
  int tid = threadIdx.x;
  __shared__ alignas(16) float At[64 * 17];
  __shared__ alignas(16) float Bt[64 * 17];
  int tx = tid & 15, ty = tid >> 4;
  int r = tid >> 2, q = tid & 3;
  float acc[4][4] = {};
  for (int d0 = 0; d0 < KS; d0 += 16) {
    float4 av = *(const float4*)&ecl[(size_t)(k0 + r) * KS + d0 + q * 4];
    float4 bv = *(const float4*)&emw[(size_t)(v0 + r) * KS + d0 + q * 4];
    __syncthreads();
    At[r * 17 + q * 4 + 0] = av.x; At[r * 17 + q * 4 + 1] = av.y;
    At[r * 17 + q * 4 + 2] = av.z; At[r * 17 + q * 4 + 3] = av.w;
    Bt[r * 17 + q * 4 + 0] = bv.x; Bt[r * 17 + q * 4 + 1] = bv.y;
    Bt[r * 17 + q * 4 + 2] = bv.z; Bt[r * 17 + q * 4 + 3] = bv.w;
    __syncthreads();
    #pragma unroll
    for (int dd = 0; dd < 16; ++dd) {
      float a[4], b[4];
      #pragma unroll
      for (int i = 0; i < 4; ++i) a[i] = At[(ty * 4 + i) * 17 + dd];
      #pragma unroll
      for (int i = 0; i < 4; ++i) b[i] = Bt[(tx * 4 + i) * 17 + dd];
      #pragma unroll
      for (int i = 0; i < 4; ++i)
        #pragma unroll
        for (int jj = 0; jj < 4; ++jj) acc[i][jj] += a[i] * b[jj];
    }
  }
  #pragma unroll
  for (int i = 0; i < 4; ++i) {
    float4 o; o.x = acc[i][0]; o.y = acc[i][1]; o.z = acc[i][2]; o.w = acc[i][3];
    *(float4*)&C[(size_t)(k0 + ty * 4 + i) * VOCAB + v0 + tx * 4] = o;
  }
}

// ---------------- per-cluster lse over vocab -----------------------------
__global__ __launch_bounds__(256) void k_lsec(const float* C, float* lseC) {
  int k = blockIdx.x, tid = threadIdx.x;
  __shared__ float sm[4], ss[4];
  const float* row = C + (size_t)k * VOCAB;
  float m = -1e30f;
  for (int v = tid; v < VOCAB; v += 256) m = fmaxf(m, row[v]);
  #pragma unroll
  for (int s = 1; s < 64; s <<= 1) m = fmaxf(m, __shfl_xor(m, s));
  if ((tid & 63) == 0) sm[tid >> 6] = m;
  __syncthreads();
  m = fmaxf(fmaxf(sm[0], sm[1]), fmaxf(sm[2], sm[3]));
  float sum = 0.f;
  for (int v = tid; v < VOCAB; v += 256) sum += __expf(row[v] - m);
  #pragma unroll
  for (int s = 1; s < 64; s <<= 1) sum += __shfl_xor(sum, s);
  if ((tid & 63) == 0) ss[tid >> 6] = sum;
  __syncthreads();
  if (tid == 0) lseC[k] = m + __logf(ss[0] + ss[1] + ss[2] + ss[3]);
}

// ---------------- gather emission log-probs emis[n][t][k] ----------------
__global__ __launch_bounds__(128) void k_emis(const int* x, const float* C, const float* lseC, float* emis) {
  int t = blockIdx.x + 1;          // 1..255
  int n = blockIdx.y;
  int k = threadIdx.x;
  int w = x[n * T_LEN + t];
  emis[(size_t)((n << 8) + t) * KS + k] = C[(size_t)k * VOCAB + w] - lseC[k];
}

// ---- big GEMM chunk (permuted c-dim): S[mloc][j*128 + i] = exp(.) fp8 ---
// Staged tiles are k-chunk-swizzled (producers wrote chunk c at c^(row&7));
// fragment reads use the matching XOR -> conflict-free ds_read_b128.
__global__ __launch_bounds__(256, 2) void k_gemm(const unsigned short* exb, const unsigned short* trb,
                                                 unsigned char* S, float* srowP, int m_base, int Rcap) {
  int bx = blockIdx.x, grp = blockIdx.y;       // grp 0..15
  int tid = threadIdx.x, wv = tid >> 6, ln = tid & 63;
  int wc = wv & 1, wm = wv >> 1;
  __shared__ alignas(16) unsigned short As[128 * 64];
  __shared__ alignas(16) unsigned short Bs[128 * 64];
  int m0 = m_base + bx * 128;                  // global row base
  int lr = ln & 15, lk = (ln >> 4) * 8;
  int lg = ln >> 4;                            // 0..3, epilogue reg-group
  floatx4 sacc[4][4] = {};                     // per-element srow partials
  for (int byi = 0; byi < 8; ++byi) {
    int by = grp * 8 + byi;                    // j-tile index (j == by)
    int c0 = by * 128;
    floatx4 acc[4][4] = {};                    // [fc][fm]; Cᵀ: rows=c(=i), cols=m
    for (int k0 = 0; k0 < EDIM; k0 += 64) {
      #pragma unroll
      for (int r = 0; r < 4; ++r) {
        int chunk = (wv * 4 + r) * 64 + ln;    // 16B chunk id in 16KB tile
        int row = chunk >> 3, c8 = chunk & 7;
        gl_lds16(&exb[(size_t)(m0 + row) * EDIM + k0 + c8 * 8], &As[(wv * 4 + r) * 512]);
        gl_lds16(&trb[(size_t)(c0 + row) * EDIM + k0 + c8 * 8], &Bs[(wv * 4 + r) * 512]);
      }
      __syncthreads();
      #pragma unroll
      for (int kk = 0; kk < 64; kk += 32) {
        int sw = ((((kk + lk) >> 3) ^ (lr & 7)) << 3);   // swizzled k-offset
        short8 af[4], bf[4];
        #pragma unroll
        for (int f = 0; f < 4; ++f)
          af[f] = *(const short8*)&As[(wm * 64 + f * 16 + lr) * 64 + sw];
        #pragma unroll
        for (int f = 0; f < 4; ++f)
          bf[f] = *(const short8*)&Bs[(wc * 64 + f * 16 + lr) * 64 + sw];
        #pragma unroll
        for (int fc = 0; fc < 4; ++fc)
          #pragma unroll
          for (int fm = 0; fm < 4; ++fm)
            acc[fc][fm] = __builtin_amdgcn_mfma_f32_16x16x32_bf16(bf[fc], af[fm], acc[fc][fm], 0, 0, 0);
      }
      __syncthreads();
    }
    // epilogue: exp, fp8 pack into LDS tile (XOR bank swizzle), srow regs
    unsigned char* Ts = (unsigned char*)As;    // reuse 16 KB
    #pragma unroll
    for (int fc = 0; fc < 4; ++fc) {
      #pragma unroll
      for (int fm = 0; fm < 4; ++fm) {
        floatx4 a = acc[fc][fm];
        float e0 = __expf(a[0]), e1 = __expf(a[1]), e2 = __expf(a[2]), e3 = __expf(a[3]);
        int p = __builtin_amdgcn_cvt_pk_fp8_f32(e0, e1, 0, 0);
        p = __builtin_amdgcn_cvt_pk_fp8_f32(e2, e3, p, 1);
        int mloc = wm * 64 + fm * 16 + lr;
        int cl = wc * 64 + fc * 16 + lg * 4;   // cl = i (tile-local)
        *(int*)&Ts[mloc * 128 + (cl ^ ((mloc & 7) << 4))] = p;
        sacc[fc][fm][0] += e0; sacc[fc][fm][1] += e1;
        sacc[fc][fm][2] += e2; sacc[fc][fm][3] += e3;
      }
    }
    __syncthreads();                           // Ts ready
    // store: natural layout S[m][j*128 + i] (swizzle only inside Ts)
    #pragma unroll
    for (int r = 0; r < 4; ++r) {
      int seg = r * 256 + tid;                 // 1024 x 16B segments
      int mloc = seg >> 3, s = seg & 7;
      uint4 v = *(const uint4*)&Ts[mloc * 128 + ((s ^ (mloc & 7)) << 4)];
      *(uint4*)&S[(size_t)(bx * 128 + mloc) * KK + c0 + s * 16] = v;
    }
    __syncthreads();                           // Ts dead before next staging
  }
  // srowP[grp][mloc][i] = partial sum over this block's 8 j values
  #pragma unroll
  for (int fc = 0; fc < 4; ++fc) {
    #pragma unroll
    for (int fm = 0; fm < 4; ++fm) {
      int mloc = bx * 128 + wm * 64 + fm * 16 + lr;
      int i = wc * 64 + fc * 16 + lg * 4;
      *(floatx4*)&srowP[((size_t)grp * Rcap + mloc) * KS + i] = sacc[fc][fm];
    }
  }
}

// ---- combine srow partials -> srowR[m][i] = 1/sum (global m indexing) ---
__global__ __launch_bounds__(256) void k_comb(const float* srowP, float* srowR,
                                              int m_base, int Rcap, int rows) {
  int id = blockIdx.x * 256 + threadIdx.x;
  if (id >= rows * KS) return;
  float s = 0.f;
  #pragma unroll
  for (int g = 0; g < GPART; ++g) s += srowP[(size_t)g * Rcap * KS + id];
  srowR[(size_t)m_base * KS + id] = 1.0f / s;
}

// ---------------- sequential forward scan chunk, one block per sequence --
// 512 threads: wave wv owns j = wv*16+(ln&15); gh = ln>>4 owns i-slice.
// Global prefetch rotated 1 full step ahead; lgkm-only barriers keep the
// prefetch loads in flight across the per-step syncs.
__global__ __launch_bounds__(512) void k_scan(const unsigned char* S, const float* srowR,
                                              const float* emis, const float* pre0,
                                              float* alphaG, float* nll, int t0, int tc) {
  int n = blockIdx.x, tid = threadIdx.x;
  int ln = tid & 63, wv = tid >> 6;
  int j  = wv * 16 + (ln & 15);
  int gh = ln >> 4;
  __shared__ alignas(16) float uL[KS];
  __shared__ float sums[KS];
  __shared__ float red[16];
  int t1 = t0 + tc;
  const float* a0 = (t0 == 1) ? pre0 : (alphaG + (size_t)n * KS);
  float pre_j = a0[j];
  float M     = a0[0];
  float rs0 = srowR[(size_t)((t0 - 1) * 64 + n) * KS + j];
  if (ln < 16) uL[j] = __expf(pre_j - M) * rs0;
  size_t rowoff = (size_t)j * 128 + gh * 32;
  const unsigned char* b0 = S + (size_t)n * KK + rowoff;
  uint4 sva = *(const uint4*)(b0);
  uint4 svb = *(const uint4*)(b0 + 16);
  // prefetch scalars for step t0 (consumed after B1 of iter t0)
  float em  = emis[(size_t)((n << 8) + t0) * KS + j];
  float em0 = emis[(size_t)((n << 8) + t0) * KS];
  float rsc = srowR[(size_t)(t0 * 64 + n) * KS + j];      // srow for u(t0+1)
  __syncthreads();                             // initial full barrier
  for (int t = t0; t < t1; ++t) {
    // prefetch next S row + next-step scalars (ride across barriers)
    int tn = (t + 1 < t1) ? (t + 1 - t0) : 0;
    const unsigned char* bn = S + (size_t)(tn * 64 + n) * KK + rowoff;
    uint4 nxa = *(const uint4*)(bn);
    uint4 nxb = *(const uint4*)(bn + 16);
    float em_n = 0.f, em0_n = 0.f, rs_n = 0.f;
    if (t + 1 < t1) {
      em_n  = emis[(size_t)((n << 8) + t + 1) * KS + j];
      em0_n = emis[(size_t)((n << 8) + t + 1) * KS];
      rs_n  = srowR[(size_t)((t + 1) * 64 + n) * KS + j];
    }
    // matvec: 32 i's for output state j
    float4 uu[8];
    const float4* up4 = (const float4*)&uL[gh * 32];
    #pragma unroll
    for (int q = 0; q < 8; ++q) uu[q] = up4[q];
    unsigned wd[8] = {sva.x, sva.y, sva.z, sva.w, svb.x, svb.y, svb.z, svb.w};
    float a0s = 0.f, a1s = 0.f;
    #pragma unroll
    for (int q = 0; q < 8; q += 2) {
      float4 c0v = cvt4_fp8(wd[q]);
      float4 c1v = cvt4_fp8(wd[q + 1]);
      a0s += c0v.x * uu[q].x + c0v.y * uu[q].y + c0v.z * uu[q].z + c0v.w * uu[q].w;
      a1s += c1v.x * uu[q + 1].x + c1v.y * uu[q + 1].y + c1v.z * uu[q + 1].z + c1v.w * uu[q + 1].w;
    }
    float a = a0s + a1s;
    a += __shfl_xor(a, 16);
    a += __shfl_xor(a, 32);
    if (ln < 16) sums[j] = a;
    LGKM_BARRIER();                            // B1: sums(t) visible
    float cj = sums[j];
    float c0 = sums[0];
    pre_j = M + __logf(cj) + em;
    M     = M + __logf(c0) + em0;
    if (t + 1 < t1) {
      if (ln < 16) uL[j] = __expf(pre_j - M) * rsc;
    }
    sva = nxa; svb = nxb; em = em_n; em0 = em0_n; rsc = rs_n;
    LGKM_BARRIER();                            // B2: uL(t+1) visible
  }
  if (ln < 16) alphaG[(size_t)n * KS + j] = pre_j;
  if (t1 == T_LEN) {
    float e = (ln < 16) ? __expf(pre_j - M) : 0.f;
    #pragma unroll
    for (int s = 1; s < 64; s <<= 1) e += __shfl_xor(e, s);
    if (ln == 0) red[wv] = e;
    __syncthreads();
    if (tid == 0) {
      float s = 0.f;
      for (int w8 = 0; w8 < 8; ++w8) s += red[w8];
      nll[n] = M + __logf(s);
    }
  }
}

// ---------------- final: out = -mean(nll) --------------------------------
__global__ __launch_bounds__(64) void k_final(const float* nll, float* out) {
  int tid = threadIdx.x;
  float v = nll[tid];
  #pragma unroll
  for (int s = 1; s < 64; s <<= 1) v += __shfl_xor(v, s);
  if (tid == 0) out[0] = -v / 64.0f;
}

extern "C" void kernel_launch(void* const* d_in, const int* in_sizes, int n_in,
                              void* d_out, int out_size, void* d_ws, size_t ws_size,
                              hipStream_t stream) {
  const int*   x       = (const int*)d_in[0];
  const float* embed_w = (const float*)d_in[1];
  const float* trans_w = (const float*)d_in[2];
  const float* start_w = (const float*)d_in[3];
  const float* start_b = (const float*)d_in[4];
  const float* ecl     = (const float*)d_in[5];
  const float* emw     = (const float*)d_in[6];

  char* w = (char*)d_ws;
  size_t off = 0;
  auto alloc = [&](size_t bytes) -> char* {
    char* p = w + off;
    off = (off + bytes + 255) & ~(size_t)255;
    return p;
  };
  float*          pre0   = (float*)alloc(KS * 4);
  float*          lseC   = (float*)alloc(KS * 4);
  float*          nll    = (float*)alloc(N_SEQ * 4);
  float*          alphaG = (float*)alloc((size_t)N_SEQ * KS * 4);
  unsigned short* trb    = (unsigned short*)alloc((size_t)KK * EDIM * 2);     // 8.39 MB (permuted+swizzled)
  unsigned short* exb    = (unsigned short*)alloc((size_t)MROWS * EDIM * 2);  // 8.39 MB (swizzled)
  float*          emis   = (float*)alloc((size_t)N_SEQ * T_LEN * KS * 4);     // 8.39 MB
  float*          srowR  = (float*)alloc((size_t)MROWS * KS * 4);             // 8.39 MB
  // chunk region: S chunk + srowP partials; also aliases transient C
  // (emission logits, dead before first k_gemm).
  char* region = w + off;
  size_t avail = (ws_size > off) ? (ws_size - off) : 0;
  float* C = (float*)region;                       // 16.38 MB transient

  // per chunk of Tc steps: R = Tc*64 rows; bytes = R*(16384 + 8192)
  int Tc = 2;
  for (int c = 2; c <= 64; c += 2)
    if ((size_t)c * 64 * 24576 <= avail) Tc = c;
  int Rcap = Tc * 64;
  unsigned char* S     = (unsigned char*)region;
  float*         srowP = (float*)(region + (size_t)Rcap * KK);

  hipLaunchKernelGGL(k_prep,       dim3(1),        dim3(128), 0, stream, start_w, start_b, pre0);
  hipLaunchKernelGGL(k_transcvt,   dim3(4096),     dim3(256), 0, stream, trans_w, trb);
  hipLaunchKernelGGL(k_embed,      dim3(16384),    dim3(256), 0, stream, x, embed_w, exb);
  hipLaunchKernelGGL(k_emitlogits, dim3(500, 2),   dim3(256), 0, stream, ecl, emw, C);
  hipLaunchKernelGGL(k_lsec,       dim3(128),      dim3(256), 0, stream, C, lseC);
  hipLaunchKernelGGL(k_emis,       dim3(255, 64),  dim3(128), 0, stream, x, C, lseC, emis);

  int t0 = 1;
  while (t0 < T_LEN) {
    int tc = T_LEN - t0; if (tc > Tc) tc = Tc;
    int m_base = (t0 - 1) * 64;
    int gx = (tc * 64 + 127) / 128;
    hipLaunchKernelGGL(k_gemm, dim3(gx, GPART), dim3(256), 0, stream, exb, trb, S, srowP, m_base, Rcap);
    hipLaunchKernelGGL(k_comb, dim3(gx * 64),   dim3(256), 0, stream, srowP, srowR, m_base, Rcap, gx * 128);
    hipLaunchKernelGGL(k_scan, dim3(64),        dim3(512), 0, stream, S, srowR, emis, pre0, alphaG, nll, t0, tc);
    t0 += tc;
  }
  hipLaunchKernelGGL(k_final, dim3(1), dim3(64), 0, stream, nll, (float*)d_out);
}

// Round 7
// 740.798 us; speedup vs baseline: 1.0095x; 1.0095x over previous
//
#include <hip/hip_runtime.h>
#include <cstdint>
#include <cstddef>

// Problem constants (fixed by reference)
#define N_SEQ 64
#define T_LEN 256
#define VOCAB 32000
#define EDIM  256
#define KS    128          // hidden states
#define KK    16384        // KS*KS
#define MROWS 16384        // padded (t,n) rows for GEMM (real: 255*64 = 16320)
#define MREAL 16320
#define GPART 16           // srow partial groups (by-split in gemm grid)

typedef short  short8  __attribute__((ext_vector_type(8)));
typedef float  floatx4 __attribute__((ext_vector_type(4)));
typedef float  floatx2 __attribute__((ext_vector_type(2)));
typedef int    intx8   __attribute__((ext_vector_type(8)));

// lgkm-only barrier: does NOT drain vmcnt, so global prefetches stay in
// flight across the barrier (CK block_sync_lds pattern).
#define LGKM_BARRIER() asm volatile("s_waitcnt lgkmcnt(0)\n\ts_barrier" ::: "memory")

static __device__ __forceinline__ unsigned short f2bf(float f) {
  unsigned u = __float_as_uint(f);
  u += 0x7fffu + ((u >> 16) & 1u);          // RNE
  return (unsigned short)(u >> 16);
}

static __device__ __forceinline__ void gl_lds16(const void* gptr, void* lptr) {
  // async global->LDS, 16B per lane; LDS dest = wave-uniform base + lane*16
  __builtin_amdgcn_global_load_lds(
      (const __attribute__((address_space(1))) void*)gptr,
      (__attribute__((address_space(3))) void*)lptr, 16, 0, 0);
}

// ---------------- start-distribution log_softmax -------------------------
__global__ __launch_bounds__(128) void k_prep(const float* sw, const float* sb, float* pre0) {
  __shared__ float vals[KS];
  __shared__ float MM, LS;
  int tid = threadIdx.x;
  float v = sw[tid] + sb[tid];
  vals[tid] = v;
  __syncthreads();
  if (tid == 0) { float m = vals[0]; for (int i = 1; i < KS; ++i) m = fmaxf(m, vals[i]); MM = m; }
  __syncthreads();
  float e = __expf(v - MM);
  vals[tid] = e;
  __syncthreads();
  if (tid == 0) { float s = 0.f; for (int i = 0; i < KS; ++i) s += vals[i]; LS = MM + __logf(s); }
  __syncthreads();
  pre0[tid] = v - LS;
}

// ------- trans_w fp32 -> bf16, ROW-PERMUTED row'=(j)*128+(i), k-SWIZZLED -
__global__ __launch_bounds__(256) void k_transcvt(const float* tw, unsigned short* tb) {
  int idx = blockIdx.x * 256 + threadIdx.x;          // over float4 groups
  if (idx >= (KK * EDIM) / 4) return;
  int row = idx >> 6, e4 = idx & 63;
  int rowp = ((row & 127) << 7) | (row >> 7);
  int e4s = (e4 & 0x31) | (((((e4 >> 1) & 7) ^ (rowp & 7))) << 1);
  float4 v = *(const float4*)&tw[(size_t)idx * 4];
  unsigned h0 = f2bf(v.x), h1 = f2bf(v.y), h2 = f2bf(v.z), h3 = f2bf(v.w);
  uint2 o; o.x = h0 | (h1 << 16); o.y = h2 | (h3 << 16);
  *(uint2*)&tb[(size_t)rowp * EDIM + e4s * 4] = o;
}

// ------- gather token embeddings -> bf16 rows m = t*64+n, k-SWIZZLED -----
__global__ __launch_bounds__(256) void k_embed(const int* x, const float* ew, unsigned short* exb) {
  int m = blockIdx.x, e = threadIdx.x;
  int t = m >> 6, n = m & 63;
  float v = 0.f;
  if (m < MREAL) { int tok = x[n * T_LEN + t]; v = ew[(size_t)tok * EDIM + e]; }
  int es = (e & 0xC7) | ((((e >> 3) & 7) ^ (m & 7)) << 3);
  exb[(size_t)m * EDIM + es] = f2bf(v);
}

// ---------------- emission logits C[k][v] = ecl[k] . emit_w[v] -----------
__global__ __launch_bounds__(256) void k_emitlogits(const float* ecl, const float* emw, float* C) {
  int v0 = blockIdx.x * 64, k0 = blockIdx.y * 64;
  int tid = threadIdx.x;
  __shared__ alignas(16) float At[64 * 17];
  __shared__ alignas(16) float Bt[64 * 17];
  int tx = tid & 15, ty = tid >> 4;
  int r = tid >> 2, q = tid & 3;
  float acc[4][4] = {};
  for (int d0 = 0; d0 < KS; d0 += 16) {
    float4 av = *(const float4*)&ecl[(size_t)(k0 + r) * KS + d0 + q * 4];
    float4 bv = *(const float4*)&emw[(size_t)(v0 + r) * KS + d0 + q * 4];
    __syncthreads();
    At[r * 17 + q * 4 + 0] = av.x; At[r * 17 + q * 4 + 1] = av.y;
    At[r * 17 + q * 4 + 2] = av.z; At[r * 17 + q * 4 + 3] = av.w;
    Bt[r * 17 + q * 4 + 0] = bv.x; Bt[r * 17 + q * 4 + 1] = bv.y;
    Bt[r * 17 + q * 4 + 2] = bv.z; Bt[r * 17 + q * 4 + 3] = bv.w;
    __syncthreads();
    #pragma unroll
    for (int dd = 0; dd < 16; ++dd) {
      float a[4], b[4];
      #pragma unroll
      for (int i = 0; i < 4; ++i) a[i] = At[(ty * 4 + i) * 17 + dd];
      #pragma unroll
      for (int i = 0; i < 4; ++i) b[i] = Bt[(tx * 4 + i) * 17 + dd];
      #pragma unroll
      for (int i = 0; i < 4; ++i)
        #pragma unroll
        for (int jj = 0; jj < 4; ++jj) acc[i][jj] += a[i] * b[jj];
    }
  }
  #pragma unroll
  for (int i = 0; i < 4; ++i) {
    float4 o; o.x = acc[i][0]; o.y = acc[i][1]; o.z = acc[i][2]; o.w = acc[i][3];
    *(float4*)&C[(size_t)(k0 + ty * 4 + i) * VOCAB + v0 + tx * 4] = o;
  }
}

// ---------------- per-cluster lse over vocab -----------------------------
__global__ __launch_bounds__(256) void k_lsec(const float* C, float* lseC) {
  int k = blockIdx.x, tid = threadIdx.x;
  __shared__ float sm[4], ss[4];
  const float* row = C + (size_t)k * VOCAB;
  float m = -1e30f;
  for (int v = tid; v < VOCAB; v += 256) m = fmaxf(m, row[v]);
  #pragma unroll
  for (int s = 1; s < 64; s <<= 1) m = fmaxf(m, __shfl_xor(m, s));
  if ((tid & 63) == 0) sm[tid >> 6] = m;
  __syncthreads();
  m = fmaxf(fmaxf(sm[0], sm[1]), fmaxf(sm[2], sm[3]));
  float sum = 0.f;
  for (int v = tid; v < VOCAB; v += 256) sum += __expf(row[v] - m);
  #pragma unroll
  for (int s = 1; s < 64; s <<= 1) sum += __shfl_xor(sum, s);
  if ((tid & 63) == 0) ss[tid >> 6] = sum;
  __syncthreads();
  if (tid == 0) lseC[k] = m + __logf(ss[0] + ss[1] + ss[2] + ss[3]);
}

// ---------------- gather emission log-probs emis[n][t][k] ----------------
__global__ __launch_bounds__(128) void k_emis(const int* x, const float* C, const float* lseC, float* emis) {
  int t = blockIdx.x + 1;          // 1..255
  int n = blockIdx.y;
  int k = threadIdx.x;
  int w = x[n * T_LEN + t];
  emis[(size_t)((n << 8) + t) * KS + k] = C[(size_t)k * VOCAB + w] - lseC[k];
}

// ---- big GEMM chunk (permuted c-dim): S[mloc][j*128 + i] = exp(.) fp8 ---
__global__ __launch_bounds__(256, 2) void k_gemm(const unsigned short* exb, const unsigned short* trb,
                                                 unsigned char* S, float* srowP, int m_base, int Rcap) {
  int bx = blockIdx.x, grp = blockIdx.y;       // grp 0..15
  int tid = threadIdx.x, wv = tid >> 6, ln = tid & 63;
  int wc = wv & 1, wm = wv >> 1;
  __shared__ alignas(16) unsigned short As[128 * 64];
  __shared__ alignas(16) unsigned short Bs[128 * 64];
  int m0 = m_base + bx * 128;                  // global row base
  int lr = ln & 15, lk = (ln >> 4) * 8;
  int lg = ln >> 4;                            // 0..3, epilogue reg-group
  floatx4 sacc[4][4] = {};                     // per-element srow partials
  for (int byi = 0; byi < 8; ++byi) {
    int by = grp * 8 + byi;                    // j-tile index (j == by)
    int c0 = by * 128;
    floatx4 acc[4][4] = {};                    // [fc][fm]; Cᵀ: rows=c(=i), cols=m
    for (int k0 = 0; k0 < EDIM; k0 += 64) {
      #pragma unroll
      for (int r = 0; r < 4; ++r) {
        int chunk = (wv * 4 + r) * 64 + ln;    // 16B chunk id in 16KB tile
        int row = chunk >> 3, c8 = chunk & 7;
        gl_lds16(&exb[(size_t)(m0 + row) * EDIM + k0 + c8 * 8], &As[(wv * 4 + r) * 512]);
        gl_lds16(&trb[(size_t)(c0 + row) * EDIM + k0 + c8 * 8], &Bs[(wv * 4 + r) * 512]);
      }
      __syncthreads();
      #pragma unroll
      for (int kk = 0; kk < 64; kk += 32) {
        int sw = ((((kk + lk) >> 3) ^ (lr & 7)) << 3);   // swizzled k-offset
        short8 af[4], bf[4];
        #pragma unroll
        for (int f = 0; f < 4; ++f)
          af[f] = *(const short8*)&As[(wm * 64 + f * 16 + lr) * 64 + sw];
        #pragma unroll
        for (int f = 0; f < 4; ++f)
          bf[f] = *(const short8*)&Bs[(wc * 64 + f * 16 + lr) * 64 + sw];
        #pragma unroll
        for (int fc = 0; fc < 4; ++fc)
          #pragma unroll
          for (int fm = 0; fm < 4; ++fm)
            acc[fc][fm] = __builtin_amdgcn_mfma_f32_16x16x32_bf16(bf[fc], af[fm], acc[fc][fm], 0, 0, 0);
      }
      __syncthreads();
    }
    // epilogue: exp, fp8 pack into LDS tile (XOR bank swizzle), srow regs
    unsigned char* Ts = (unsigned char*)As;    // reuse 16 KB
    #pragma unroll
    for (int fc = 0; fc < 4; ++fc) {
      #pragma unroll
      for (int fm = 0; fm < 4; ++fm) {
        floatx4 a = acc[fc][fm];
        float e0 = __expf(a[0]), e1 = __expf(a[1]), e2 = __expf(a[2]), e3 = __expf(a[3]);
        int p = __builtin_amdgcn_cvt_pk_fp8_f32(e0, e1, 0, 0);
        p = __builtin_amdgcn_cvt_pk_fp8_f32(e2, e3, p, 1);
        int mloc = wm * 64 + fm * 16 + lr;
        int cl = wc * 64 + fc * 16 + lg * 4;   // cl = i (tile-local)
        *(int*)&Ts[mloc * 128 + (cl ^ ((mloc & 7) << 4))] = p;
        sacc[fc][fm][0] += e0; sacc[fc][fm][1] += e1;
        sacc[fc][fm][2] += e2; sacc[fc][fm][3] += e3;
      }
    }
    __syncthreads();                           // Ts ready
    // store: natural layout S[m][j*128 + i] (swizzle only inside Ts)
    #pragma unroll
    for (int r = 0; r < 4; ++r) {
      int seg = r * 256 + tid;                 // 1024 x 16B segments
      int mloc = seg >> 3, s = seg & 7;
      uint4 v = *(const uint4*)&Ts[mloc * 128 + ((s ^ (mloc & 7)) << 4)];
      *(uint4*)&S[(size_t)(bx * 128 + mloc) * KK + c0 + s * 16] = v;
    }
    __syncthreads();                           // Ts dead before next staging
  }
  // srowP[grp][mloc][i] = partial sum over this block's 8 j values
  #pragma unroll
  for (int fc = 0; fc < 4; ++fc) {
    #pragma unroll
    for (int fm = 0; fm < 4; ++fm) {
      int mloc = bx * 128 + wm * 64 + fm * 16 + lr;
      int i = wc * 64 + fc * 16 + lg * 4;
      *(floatx4*)&srowP[((size_t)grp * Rcap + mloc) * KS + i] = sacc[fc][fm];
    }
  }
}

// ---- combine srow partials -> srowR[m][i] = 1/sum (global m indexing) ---
__global__ __launch_bounds__(256) void k_comb(const float* srowP, float* srowR,
                                              int m_base, int Rcap, int rows) {
  int id = blockIdx.x * 256 + threadIdx.x;
  if (id >= rows * KS) return;
  float s = 0.f;
  #pragma unroll
  for (int g = 0; g < GPART; ++g) s += srowP[(size_t)g * Rcap * KS + id];
  srowR[(size_t)m_base * KS + id] = 1.0f / s;
}

// ---------------- sequential forward scan chunk, one block per sequence --
// MFMA-based: per step each wave does ONE v_mfma_scale 16x16x128 (fp8 u x
// fp8 S) computing c_j for its 16 j's. u broadcast to all 16 A-rows ->
// every lane holds c_j directly (no sums LDS). S rows load straight from
// global into B-fragments. u requantized to fp8 each step with global-max
// reference (2^13 scale). 2 lgkm barriers/step.
__global__ __launch_bounds__(512) void k_scan(const unsigned char* S, const float* srowR,
                                              const float* emis, const float* pre0,
                                              float* alphaG, float* nll, int t0, int tc) {
  int n = blockIdx.x, tid = threadIdx.x;
  int ln = tid & 63, wv = tid >> 6;
  int j  = wv * 16 + (ln & 15);
  int kg = ln >> 4;                            // 0..3, 32-wide k-group
  __shared__ alignas(16) unsigned char uL8[KS];
  __shared__ alignas(16) float red[8];
  __shared__ float red2[8];
  const float LN8192 = 9.010913347f;           // 13*ln2
  int t1 = t0 + tc;
  const float* a0 = (t0 == 1) ? pre0 : (alphaG + (size_t)n * KS);
  float pre_j = a0[j];
  // init: global max of pre
  float mxw = pre_j;
  #pragma unroll
  for (int s2 = 1; s2 < 16; s2 <<= 1) mxw = fmaxf(mxw, __shfl_xor(mxw, s2));
  if (ln == 0) red[wv] = mxw;
  __syncthreads();
  float4 ra = *(const float4*)&red[0];
  float4 rb = *(const float4*)&red[4];
  float Mx = fmaxf(fmaxf(fmaxf(ra.x, ra.y), fmaxf(ra.z, ra.w)),
                   fmaxf(fmaxf(rb.x, rb.y), fmaxf(rb.z, rb.w)));
  {
    float rs0 = srowR[(size_t)((t0 - 1) * 64 + n) * KS + j];
    float up = __expf(pre_j - Mx) * rs0 * 8192.0f;
    int q = __builtin_amdgcn_cvt_pk_fp8_f32(up, up, 0, 0);
    if (ln < 16) uL8[j] = (unsigned char)(q & 0xff);
  }
  __syncthreads();
  intx8 uf;
  {
    uint4 ua = *(const uint4*)&uL8[kg * 32];
    uint4 ub = *(const uint4*)&uL8[kg * 32 + 16];
    uf[0] = ua.x; uf[1] = ua.y; uf[2] = ua.z; uf[3] = ua.w;
    uf[4] = ub.x; uf[5] = ub.y; uf[6] = ub.z; uf[7] = ub.w;
  }
  size_t rowoff = (size_t)j * 128 + kg * 32;
  intx8 sf;
  {
    const unsigned char* b0 = S + (size_t)n * KK + rowoff;
    uint4 sa = *(const uint4*)(b0);
    uint4 sb = *(const uint4*)(b0 + 16);
    sf[0] = sa.x; sf[1] = sa.y; sf[2] = sa.z; sf[3] = sa.w;
    sf[4] = sb.x; sf[5] = sb.y; sf[6] = sb.z; sf[7] = sb.w;
  }
  float em  = emis[(size_t)((n << 8) + t0) * KS + j];
  float rs1 = srowR[(size_t)(t0 * 64 + n) * KS + j];  // for u(t0+1)
  float Mxp = Mx;
  for (int t = t0; t < t1; ++t) {
    // prefetch S(t+1) + scalars (ride across lgkm barriers)
    int tn = (t + 1 < t1) ? (t + 1 - t0) : 0;
    const unsigned char* bn = S + (size_t)(tn * 64 + n) * KK + rowoff;
    uint4 na = *(const uint4*)(bn);
    uint4 nb = *(const uint4*)(bn + 16);
    float em_n = (t + 1 < t1) ? emis[(size_t)((n << 8) + t + 1) * KS + j] : 0.f;
    float rs_n = (t + 1 < T_LEN - 1) ? srowR[(size_t)((t + 1) * 64 + n) * KS + j] : 0.f;
    floatx4 cz = {0.f, 0.f, 0.f, 0.f};
    floatx4 d = __builtin_amdgcn_mfma_scale_f32_16x16x128_f8f6f4(
        uf, sf, cz, 0, 0, 0, 0x7F7F7F7F, 0, 0x7F7F7F7F);
    pre_j = Mxp - LN8192 + __logf(d[0]) + em;
    float mw = pre_j;
    #pragma unroll
    for (int s2 = 1; s2 < 16; s2 <<= 1) mw = fmaxf(mw, __shfl_xor(mw, s2));
    if (ln == 0) red[wv] = mw;
    LGKM_BARRIER();                            // B1: red(t) visible
    float4 xa = *(const float4*)&red[0];
    float4 xb = *(const float4*)&red[4];
    Mx = fmaxf(fmaxf(fmaxf(xa.x, xa.y), fmaxf(xa.z, xa.w)),
               fmaxf(fmaxf(xb.x, xb.y), fmaxf(xb.z, xb.w)));
    float up = __expf(pre_j - Mx) * rs1 * 8192.0f;
    int q = __builtin_amdgcn_cvt_pk_fp8_f32(up, up, 0, 0);
    if (ln < 16) uL8[j] = (unsigned char)(q & 0xff);
    LGKM_BARRIER();                            // B2: uL8(t+1) visible
    {
      uint4 ua = *(const uint4*)&uL8[kg * 32];
      uint4 ub = *(const uint4*)&uL8[kg * 32 + 16];
      uf[0] = ua.x; uf[1] = ua.y; uf[2] = ua.z; uf[3] = ua.w;
      uf[4] = ub.x; uf[5] = ub.y; uf[6] = ub.z; uf[7] = ub.w;
    }
    sf[0] = na.x; sf[1] = na.y; sf[2] = na.z; sf[3] = na.w;
    sf[4] = nb.x; sf[5] = nb.y; sf[6] = nb.z; sf[7] = nb.w;
    Mxp = Mx; em = em_n; rs1 = rs_n;
  }
  if (ln < 16) alphaG[(size_t)n * KS + j] = pre_j;
  if (t1 == T_LEN) {
    float m2 = pre_j;
    #pragma unroll
    for (int s2 = 1; s2 < 16; s2 <<= 1) m2 = fmaxf(m2, __shfl_xor(m2, s2));
    if (ln == 0) red[wv] = m2;
    __syncthreads();
    float4 xa = *(const float4*)&red[0];
    float4 xb = *(const float4*)&red[4];
    float Mg = fmaxf(fmaxf(fmaxf(xa.x, xa.y), fmaxf(xa.z, xa.w)),
                     fmaxf(fmaxf(xb.x, xb.y), fmaxf(xb.z, xb.w)));
    float e = (ln < 16) ? __expf(pre_j - Mg) : 0.f;
    #pragma unroll
    for (int s2 = 1; s2 < 16; s2 <<= 1) e += __shfl_xor(e, s2);
    if (ln == 0) red2[wv] = e;
    __syncthreads();
    if (tid == 0) {
      float s = 0.f;
      for (int w8 = 0; w8 < 8; ++w8) s += red2[w8];
      nll[n] = Mg + __logf(s);
    }
  }
}

// ---------------- final: out = -mean(nll) --------------------------------
__global__ __launch_bounds__(64) void k_final(const float* nll, float* out) {
  int tid = threadIdx.x;
  float v = nll[tid];
  #pragma unroll
  for (int s = 1; s < 64; s <<= 1) v += __shfl_xor(v, s);
  if (tid == 0) out[0] = -v / 64.0f;
}

extern "C" void kernel_launch(void* const* d_in, const int* in_sizes, int n_in,
                              void* d_out, int out_size, void* d_ws, size_t ws_size,
                              hipStream_t stream) {
  const int*   x       = (const int*)d_in[0];
  const float* embed_w = (const float*)d_in[1];
  const float* trans_w = (const float*)d_in[2];
  const float* start_w = (const float*)d_in[3];
  const float* start_b = (const float*)d_in[4];
  const float* ecl     = (const float*)d_in[5];
  const float* emw     = (const float*)d_in[6];

  char* w = (char*)d_ws;
  size_t off = 0;
  auto alloc = [&](size_t bytes) -> char* {
    char* p = w + off;
    off = (off + bytes + 255) & ~(size_t)255;
    return p;
  };
  float*          pre0   = (float*)alloc(KS * 4);
  float*          lseC   = (float*)alloc(KS * 4);
  float*          nll    = (float*)alloc(N_SEQ * 4);
  float*          alphaG = (float*)alloc((size_t)N_SEQ * KS * 4);
  unsigned short* trb    = (unsigned short*)alloc((size_t)KK * EDIM * 2);     // 8.39 MB (permuted+swizzled)
  unsigned short* exb    = (unsigned short*)alloc((size_t)MROWS * EDIM * 2);  // 8.39 MB (swizzled)
  float*          emis   = (float*)alloc((size_t)N_SEQ * T_LEN * KS * 4);     // 8.39 MB
  float*          srowR  = (float*)alloc((size_t)MROWS * KS * 4);             // 8.39 MB
  // chunk region: S chunk + srowP partials; also aliases transient C
  char* region = w + off;
  size_t avail = (ws_size > off) ? (ws_size - off) : 0;
  float* C = (float*)region;                       // 16.38 MB transient

  // per chunk of Tc steps: R = Tc*64 rows; bytes = R*(16384 + 8192)
  int Tc = 2;
  for (int c = 2; c <= 64; c += 2)
    if ((size_t)c * 64 * 24576 <= avail) Tc = c;
  int Rcap = Tc * 64;
  unsigned char* S     = (unsigned char*)region;
  float*         srowP = (float*)(region + (size_t)Rcap * KK);

  hipLaunchKernelGGL(k_prep,       dim3(1),        dim3(128), 0, stream, start_w, start_b, pre0);
  hipLaunchKernelGGL(k_transcvt,   dim3(4096),     dim3(256), 0, stream, trans_w, trb);
  hipLaunchKernelGGL(k_embed,      dim3(16384),    dim3(256), 0, stream, x, embed_w, exb);
  hipLaunchKernelGGL(k_emitlogits, dim3(500, 2),   dim3(256), 0, stream, ecl, emw, C);
  hipLaunchKernelGGL(k_lsec,       dim3(128),      dim3(256), 0, stream, C, lseC);
  hipLaunchKernelGGL(k_emis,       dim3(255, 64),  dim3(128), 0, stream, x, C, lseC, emis);

  int t0 = 1;
  while (t0 < T_LEN) {
    int tc = T_LEN - t0; if (tc > Tc) tc = Tc;
    int m_base = (t0 - 1) * 64;
    int gx = (tc * 64 + 127) / 128;
    hipLaunchKernelGGL(k_gemm, dim3(gx, GPART), dim3(256), 0, stream, exb, trb, S, srowP, m_base, Rcap);
    hipLaunchKernelGGL(k_comb, dim3(gx * 64),   dim3(256), 0, stream, srowP, srowR, m_base, Rcap, gx * 128);
    hipLaunchKernelGGL(k_scan, dim3(64),        dim3(512), 0, stream, S, srowR, emis, pre0, alphaG, nll, t0, tc);
    t0 += tc;
  }
  hipLaunchKernelGGL(k_final, dim3(1), dim3(64), 0, stream, nll, (float*)d_out);
}

// Round 8
// 669.414 us; speedup vs baseline: 1.1172x; 1.1066x over previous
//
#include <hip/hip_runtime.h>
#include <cstdint>
#include <cstddef>

// Problem constants (fixed by reference)
#define N_SEQ 64
#define T_LEN 256
#define VOCAB 32000
#define EDIM  256
#define KS    128          // hidden states
#define KK    16384        // KS*KS
#define MROWS 16384        // padded (t,n) rows for GEMM (real: 255*64 = 16320)
#define MREAL 16320
#define GPART 16           // srow partial groups (by-split in gemm grid)

typedef short  short8  __attribute__((ext_vector_type(8)));
typedef float  floatx4 __attribute__((ext_vector_type(4)));
typedef float  floatx2 __attribute__((ext_vector_type(2)));
typedef int    intx8   __attribute__((ext_vector_type(8)));

// lgkm-only barrier: does NOT drain vmcnt, so global stores/loads stay in
// flight across the barrier (CK block_sync_lds pattern).
#define LGKM_BARRIER() asm volatile("s_waitcnt lgkmcnt(0)\n\ts_barrier" ::: "memory")
#define LGKM_WAIT()    asm volatile("s_waitcnt lgkmcnt(0)" ::: "memory")

static __device__ __forceinline__ unsigned short f2bf(float f) {
  unsigned u = __float_as_uint(f);
  u += 0x7fffu + ((u >> 16) & 1u);          // RNE
  return (unsigned short)(u >> 16);
}

static __device__ __forceinline__ void gl_lds16(const void* gptr, void* lptr) {
  // async global->LDS, 16B per lane; LDS dest = wave-uniform base + lane*16
  __builtin_amdgcn_global_load_lds(
      (const __attribute__((address_space(1))) void*)gptr,
      (__attribute__((address_space(3))) void*)lptr, 16, 0, 0);
}

// ---------------- start-distribution log_softmax -------------------------
__global__ __launch_bounds__(128) void k_prep(const float* sw, const float* sb, float* pre0) {
  __shared__ float vals[KS];
  __shared__ float MM, LS;
  int tid = threadIdx.x;
  float v = sw[tid] + sb[tid];
  vals[tid] = v;
  __syncthreads();
  if (tid == 0) { float m = vals[0]; for (int i = 1; i < KS; ++i) m = fmaxf(m, vals[i]); MM = m; }
  __syncthreads();
  float e = __expf(v - MM);
  vals[tid] = e;
  __syncthreads();
  if (tid == 0) { float s = 0.f; for (int i = 0; i < KS; ++i) s += vals[i]; LS = MM + __logf(s); }
  __syncthreads();
  pre0[tid] = v - LS;
}

// ------- trans_w fp32 -> bf16, ROW-PERMUTED row'=(j)*128+(i), k-SWIZZLED -
__global__ __launch_bounds__(256) void k_transcvt(const float* tw, unsigned short* tb) {
  int idx = blockIdx.x * 256 + threadIdx.x;          // over float4 groups
  if (idx >= (KK * EDIM) / 4) return;
  int row = idx >> 6, e4 = idx & 63;
  int rowp = ((row & 127) << 7) | (row >> 7);
  int e4s = (e4 & 0x31) | (((((e4 >> 1) & 7) ^ (rowp & 7))) << 1);
  float4 v = *(const float4*)&tw[(size_t)idx * 4];
  unsigned h0 = f2bf(v.x), h1 = f2bf(v.y), h2 = f2bf(v.z), h3 = f2bf(v.w);
  uint2 o; o.x = h0 | (h1 << 16); o.y = h2 | (h3 << 16);
  *(uint2*)&tb[(size_t)rowp * EDIM + e4s * 4] = o;
}

// ------- gather token embeddings -> bf16 rows m = t*64+n, k-SWIZZLED -----
__global__ __launch_bounds__(256) void k_embed(const int* x, const float* ew, unsigned short* exb) {
  int m = blockIdx.x, e = threadIdx.x;
  int t = m >> 6, n = m & 63;
  float v = 0.f;
  if (m < MREAL) { int tok = x[n * T_LEN + t]; v = ew[(size_t)tok * EDIM + e]; }
  int es = (e & 0xC7) | ((((e >> 3) & 7) ^ (m & 7)) << 3);
  exb[(size_t)m * EDIM + es] = f2bf(v);
}

// ---------------- emission logits C[k][v] = ecl[k] . emit_w[v] -----------
__global__ __launch_bounds__(256) void k_emitlogits(const float* ecl, const float* emw, float* C) {
  int v0 = blockIdx.x * 64, k0 = blockIdx.y * 64;
  int tid = threadIdx.x;
  __shared__ alignas(16) float At[64 * 17];
  __shared__ alignas(16) float Bt[64 * 17];
  int tx = tid & 15, ty = tid >> 4;
  int r = tid >> 2, q = tid & 3;
  float acc[4][4] = {};
  for (int d0 = 0; d0 < KS; d0 += 16) {
    float4 av = *(const float4*)&ecl[(size_t)(k0 + r) * KS + d0 + q * 4];
    float4 bv = *(const float4*)&emw[(size_t)(v0 + r) * KS + d0 + q * 4];
    __syncthreads();
    At[r * 17 + q * 4 + 0] = av.x; At[r * 17 + q * 4 + 1] = av.y;
    At[r * 17 + q * 4 + 2] = av.z; At[r * 17 + q * 4 + 3] = av.w;
    Bt[r * 17 + q * 4 + 0] = bv.x; Bt[r * 17 + q * 4 + 1] = bv.y;
    Bt[r * 17 + q * 4 + 2] = bv.z; Bt[r * 17 + q * 4 + 3] = bv.w;
    __syncthreads();
    #pragma unroll
    for (int dd = 0; dd < 16; ++dd) {
      float a[4], b[4];
      #pragma unroll
      for (int i = 0; i < 4; ++i) a[i] = At[(ty * 4 + i) * 17 + dd];
      #pragma unroll
      for (int i = 0; i < 4; ++i) b[i] = Bt[(tx * 4 + i) * 17 + dd];
      #pragma unroll
      for (int i = 0; i < 4; ++i)
        #pragma unroll
        for (int jj = 0; jj < 4; ++jj) acc[i][jj] += a[i] * b[jj];
    }
  }
  #pragma unroll
  for (int i = 0; i < 4; ++i) {
    float4 o; o.x = acc[i][0]; o.y = acc[i][1]; o.z = acc[i][2]; o.w = acc[i][3];
    *(float4*)&C[(size_t)(k0 + ty * 4 + i) * VOCAB + v0 + tx * 4] = o;
  }
}

// ---------------- per-cluster lse over vocab -----------------------------
__global__ __launch_bounds__(256) void k_lsec(const float* C, float* lseC) {
  int k = blockIdx.x, tid = threadIdx.x;
  __shared__ float sm[4], ss[4];
  const float* row = C + (size_t)k * VOCAB;
  float m = -1e30f;
  for (int v = tid; v < VOCAB; v += 256) m = fmaxf(m, row[v]);
  #pragma unroll
  for (int s = 1; s < 64; s <<= 1) m = fmaxf(m, __shfl_xor(m, s));
  if ((tid & 63) == 0) sm[tid >> 6] = m;
  __syncthreads();
  m = fmaxf(fmaxf(sm[0], sm[1]), fmaxf(sm[2], sm[3]));
  float sum = 0.f;
  for (int v = tid; v < VOCAB; v += 256) sum += __expf(row[v] - m);
  #pragma unroll
  for (int s = 1; s < 64; s <<= 1) sum += __shfl_xor(sum, s);
  if ((tid & 63) == 0) ss[tid >> 6] = sum;
  __syncthreads();
  if (tid == 0) lseC[k] = m + __logf(ss[0] + ss[1] + ss[2] + ss[3]);
}

// ------- gather emission log-probs emis[n][t][k] + per-(n,t) max ---------
__global__ __launch_bounds__(128) void k_emis(const int* x, const float* C, const float* lseC,
                                              float* emis, float* emax) {
  int t = blockIdx.x + 1;          // 1..255
  int n = blockIdx.y;
  int k = threadIdx.x;
  __shared__ float red[2];
  int w = x[n * T_LEN + t];
  float v = C[(size_t)k * VOCAB + w] - lseC[k];
  emis[(size_t)((n << 8) + t) * KS + k] = v;
  float m = v;
  #pragma unroll
  for (int s = 1; s < 64; s <<= 1) m = fmaxf(m, __shfl_xor(m, s));
  if ((k & 63) == 0) red[k >> 6] = m;
  __syncthreads();
  if (k == 0) emax[n * T_LEN + t] = fmaxf(red[0], red[1]);
}

// ---- big GEMM chunk (permuted c-dim): S[mloc][j*128 + i] = exp(.) fp8 ---
__global__ __launch_bounds__(256, 2) void k_gemm(const unsigned short* exb, const unsigned short* trb,
                                                 unsigned char* S, float* srowP, int m_base, int Rcap) {
  int bx = blockIdx.x, grp = blockIdx.y;       // grp 0..15
  int tid = threadIdx.x, wv = tid >> 6, ln = tid & 63;
  int wc = wv & 1, wm = wv >> 1;
  __shared__ alignas(16) unsigned short As[128 * 64];
  __shared__ alignas(16) unsigned short Bs[128 * 64];
  int m0 = m_base + bx * 128;                  // global row base
  int lr = ln & 15, lk = (ln >> 4) * 8;
  int lg = ln >> 4;                            // 0..3, epilogue reg-group
  floatx4 sacc[4][4] = {};                     // per-element srow partials
  for (int byi = 0; byi < 8; ++byi) {
    int by = grp * 8 + byi;                    // j-tile index (j == by)
    int c0 = by * 128;
    floatx4 acc[4][4] = {};                    // [fc][fm]; Cᵀ: rows=c(=i), cols=m
    for (int k0 = 0; k0 < EDIM; k0 += 64) {
      #pragma unroll
      for (int r = 0; r < 4; ++r) {
        int chunk = (wv * 4 + r) * 64 + ln;    // 16B chunk id in 16KB tile
        int row = chunk >> 3, c8 = chunk & 7;
        gl_lds16(&exb[(size_t)(m0 + row) * EDIM + k0 + c8 * 8], &As[(wv * 4 + r) * 512]);
        gl_lds16(&trb[(size_t)(c0 + row) * EDIM + k0 + c8 * 8], &Bs[(wv * 4 + r) * 512]);
      }
      __syncthreads();                         // staging arrival (vmcnt drain)
      #pragma unroll
      for (int kk = 0; kk < 64; kk += 32) {
        int sw = ((((kk + lk) >> 3) ^ (lr & 7)) << 3);   // swizzled k-offset
        short8 af[4], bf[4];
        #pragma unroll
        for (int f = 0; f < 4; ++f)
          af[f] = *(const short8*)&As[(wm * 64 + f * 16 + lr) * 64 + sw];
        #pragma unroll
        for (int f = 0; f < 4; ++f)
          bf[f] = *(const short8*)&Bs[(wc * 64 + f * 16 + lr) * 64 + sw];
        #pragma unroll
        for (int fc = 0; fc < 4; ++fc)
          #pragma unroll
          for (int fm = 0; fm < 4; ++fm)
            acc[fc][fm] = __builtin_amdgcn_mfma_f32_16x16x32_bf16(bf[fc], af[fm], acc[fc][fm], 0, 0, 0);
      }
      LGKM_BARRIER();                          // LDS reads done; stores fly on
    }
    // epilogue: exp, fp8 pack into LDS tile (XOR bank swizzle), srow regs
    unsigned char* Ts = (unsigned char*)As;    // reuse 16 KB
    #pragma unroll
    for (int fc = 0; fc < 4; ++fc) {
      #pragma unroll
      for (int fm = 0; fm < 4; ++fm) {
        floatx4 a = acc[fc][fm];
        float e0 = __expf(a[0]), e1 = __expf(a[1]), e2 = __expf(a[2]), e3 = __expf(a[3]);
        int p = __builtin_amdgcn_cvt_pk_fp8_f32(e0, e1, 0, 0);
        p = __builtin_amdgcn_cvt_pk_fp8_f32(e2, e3, p, 1);
        int mloc = wm * 64 + fm * 16 + lr;
        int cl = wc * 64 + fc * 16 + lg * 4;   // cl = i (tile-local)
        *(int*)&Ts[mloc * 128 + (cl ^ ((mloc & 7) << 4))] = p;
        sacc[fc][fm][0] += e0; sacc[fc][fm][1] += e1;
        sacc[fc][fm][2] += e2; sacc[fc][fm][3] += e3;
      }
    }
    LGKM_BARRIER();                            // Ts ready
    // store: natural layout S[m][j*128 + i] (swizzle only inside Ts)
    #pragma unroll
    for (int r = 0; r < 4; ++r) {
      int seg = r * 256 + tid;                 // 1024 x 16B segments
      int mloc = seg >> 3, s = seg & 7;
      uint4 v = *(const uint4*)&Ts[mloc * 128 + ((s ^ (mloc & 7)) << 4)];
      *(uint4*)&S[(size_t)(bx * 128 + mloc) * KK + c0 + s * 16] = v;
    }
    LGKM_BARRIER();                            // Ts reads in regs; next staging ok
  }
  // srowP[grp][mloc][i] = partial sum over this block's 8 j values
  #pragma unroll
  for (int fc = 0; fc < 4; ++fc) {
    #pragma unroll
    for (int fm = 0; fm < 4; ++fm) {
      int mloc = bx * 128 + wm * 64 + fm * 16 + lr;
      int i = wc * 64 + fc * 16 + lg * 4;
      *(floatx4*)&srowP[((size_t)grp * Rcap + mloc) * KS + i] = sacc[fc][fm];
    }
  }
}

// ---- combine srow partials -> srowR[m][i] = 1/sum (global m indexing) ---
__global__ __launch_bounds__(256) void k_comb(const float* srowP, float* srowR,
                                              int m_base, int Rcap, int rows) {
  int id = blockIdx.x * 256 + threadIdx.x;
  if (id >= rows * KS) return;
  float s = 0.f;
  #pragma unroll
  for (int g = 0; g < GPART; ++g) s += srowP[(size_t)g * Rcap * KS + id];
  srowR[(size_t)m_base * KS + id] = 1.0f / s;
}

// ---------------- sequential forward scan chunk, ONE WAVE per sequence ---
// Fully replicated: the wave computes all 128 c_j per step via 8 MFMAs.
// No barriers, no cross-wave traffic. Scale reference M tracked via
// M(t) = M(t-1) + emax(n,t) + log(c0) - lnSCALE (c0 via readfirstlane).
__global__ __launch_bounds__(64, 1) void k_scan(const unsigned char* S, const float* srowR,
                                                const float* emis, const float* emax,
                                                const float* pre0, float* alphaG, float* nll,
                                                int t0, int tc) {
  int n = blockIdx.x;
  int L = threadIdx.x;                        // 0..63
  int l15 = L & 15, kg = L >> 4;              // lane's col / 32-wide k-group
  __shared__ alignas(16) unsigned char uL8[KS];
  const float SCALE = 4096.0f;
  const float LNS = 8.317766167f;             // ln(4096)
  int t1 = t0 + tc;
  const float* a0 = (t0 == 1) ? pre0 : (alphaG + (size_t)n * KS);
  float pre[8];
  #pragma unroll
  for (int q = 0; q < 8; ++q) pre[q] = a0[q * 16 + l15];
  // chunk-start M = true max (intra-wave, one-time)
  float mx = pre[0];
  #pragma unroll
  for (int q = 1; q < 8; ++q) mx = fmaxf(mx, pre[q]);
  #pragma unroll
  for (int s2 = 1; s2 < 16; s2 <<= 1) mx = fmaxf(mx, __shfl_xor(mx, s2));
  float M = mx;
  // u(t0)
  #pragma unroll
  for (int q = 0; q < 8; ++q) {
    float r0 = srowR[(size_t)((t0 - 1) * 64 + n) * KS + q * 16 + l15];
    float up = __expf(pre[q] - M) * r0 * SCALE;
    int pk = __builtin_amdgcn_cvt_pk_fp8_f32(up, up, 0, 0);
    uL8[q * 16 + l15] = (unsigned char)(pk & 0xff);
  }
  LGKM_WAIT();
  intx8 uf;
  {
    uint4 ua = *(const uint4*)&uL8[kg * 32];
    uint4 ub = *(const uint4*)&uL8[kg * 32 + 16];
    uf[0] = ua.x; uf[1] = ua.y; uf[2] = ua.z; uf[3] = ua.w;
    uf[4] = ub.x; uf[5] = ub.y; uf[6] = ub.z; uf[7] = ub.w;
  }
  intx8 sf[8];
  {
    const unsigned char* Sb = S + (size_t)n * KK;
    #pragma unroll
    for (int q = 0; q < 8; ++q) {
      const uint4* p = (const uint4*)(Sb + (size_t)(q * 16 + l15) * 128 + kg * 32);
      uint4 a = p[0], b = p[1];
      sf[q][0] = a.x; sf[q][1] = a.y; sf[q][2] = a.z; sf[q][3] = a.w;
      sf[q][4] = b.x; sf[q][5] = b.y; sf[q][6] = b.z; sf[q][7] = b.w;
    }
  }
  float em[8], rs[8];
  #pragma unroll
  for (int q = 0; q < 8; ++q) {
    em[q] = emis[(size_t)((n << 8) + t0) * KS + q * 16 + l15];
    rs[q] = srowR[(size_t)(t0 * 64 + n) * KS + q * 16 + l15];   // for u(t0+1)
  }
  float exR = emax[n * T_LEN + t0];
  for (int t = t0; t < t1; ++t) {
    // prefetch step t+1 (rides until consumed at loop bottom)
    int tp = (t + 1 < t1) ? (t + 1) : t;
    int tn = tp - t0;
    intx8 nf[8];
    {
      const unsigned char* Sn = S + (size_t)(tn * 64 + n) * KK;
      #pragma unroll
      for (int q = 0; q < 8; ++q) {
        const uint4* p = (const uint4*)(Sn + (size_t)(q * 16 + l15) * 128 + kg * 32);
        uint4 a = p[0], b = p[1];
        nf[q][0] = a.x; nf[q][1] = a.y; nf[q][2] = a.z; nf[q][3] = a.w;
        nf[q][4] = b.x; nf[q][5] = b.y; nf[q][6] = b.z; nf[q][7] = b.w;
      }
    }
    float emn[8], rsn[8];
    #pragma unroll
    for (int q = 0; q < 8; ++q) {
      emn[q] = emis[(size_t)((n << 8) + tp) * KS + q * 16 + l15];
      rsn[q] = srowR[(size_t)(tp * 64 + n) * KS + q * 16 + l15];
    }
    float exN = emax[n * T_LEN + tp];
    // 8 MFMAs: c_j for all 128 j (lane holds j = 16q + l15)
    floatx4 cz = {0.f, 0.f, 0.f, 0.f};
    float cv[8];
    #pragma unroll
    for (int q = 0; q < 8; ++q) {
      floatx4 d = __builtin_amdgcn_mfma_scale_f32_16x16x128_f8f6f4(
          uf, sf[q], cz, 0, 0, 0, 0x7F7F7F7F, 0, 0x7F7F7F7F);
      cv[q] = d[0];
    }
    float c0 = __uint_as_float(__builtin_amdgcn_readfirstlane(__float_as_uint(cv[0])));
    float Mn = M + exR + __logf(c0) - LNS;
    #pragma unroll
    for (int q = 0; q < 8; ++q) pre[q] = M - LNS + __logf(cv[q]) + em[q];
    M = Mn;
    if (t + 1 < t1) {
      #pragma unroll
      for (int q = 0; q < 8; ++q) {
        float up = __expf(pre[q] - M) * rs[q] * SCALE;
        int pk = __builtin_amdgcn_cvt_pk_fp8_f32(up, up, 0, 0);
        uL8[q * 16 + l15] = (unsigned char)(pk & 0xff);
      }
      LGKM_WAIT();
      uint4 ua = *(const uint4*)&uL8[kg * 32];
      uint4 ub = *(const uint4*)&uL8[kg * 32 + 16];
      uf[0] = ua.x; uf[1] = ua.y; uf[2] = ua.z; uf[3] = ua.w;
      uf[4] = ub.x; uf[5] = ub.y; uf[6] = ub.z; uf[7] = ub.w;
    }
    #pragma unroll
    for (int q = 0; q < 8; ++q) sf[q] = nf[q];
    #pragma unroll
    for (int q = 0; q < 8; ++q) { em[q] = emn[q]; rs[q] = rsn[q]; }
    exR = exN;
  }
  #pragma unroll
  for (int q = 0; q < 8; ++q) alphaG[(size_t)n * KS + q * 16 + l15] = pre[q];
  if (t1 == T_LEN) {
    float m2 = pre[0];
    #pragma unroll
    for (int q = 1; q < 8; ++q) m2 = fmaxf(m2, pre[q]);
    #pragma unroll
    for (int s2 = 1; s2 < 16; s2 <<= 1) m2 = fmaxf(m2, __shfl_xor(m2, s2));
    float e = 0.f;
    #pragma unroll
    for (int q = 0; q < 8; ++q) e += __expf(pre[q] - m2);
    #pragma unroll
    for (int s2 = 1; s2 < 16; s2 <<= 1) e += __shfl_xor(e, s2);
    if (L == 0) nll[n] = m2 + __logf(e);
  }
}

// ---------------- final: out = -mean(nll) --------------------------------
__global__ __launch_bounds__(64) void k_final(const float* nll, float* out) {
  int tid = threadIdx.x;
  float v = nll[tid];
  #pragma unroll
  for (int s = 1; s < 64; s <<= 1) v += __shfl_xor(v, s);
  if (tid == 0) out[0] = -v / 64.0f;
}

extern "C" void kernel_launch(void* const* d_in, const int* in_sizes, int n_in,
                              void* d_out, int out_size, void* d_ws, size_t ws_size,
                              hipStream_t stream) {
  const int*   x       = (const int*)d_in[0];
  const float* embed_w = (const float*)d_in[1];
  const float* trans_w = (const float*)d_in[2];
  const float* start_w = (const float*)d_in[3];
  const float* start_b = (const float*)d_in[4];
  const float* ecl     = (const float*)d_in[5];
  const float* emw     = (const float*)d_in[6];

  char* w = (char*)d_ws;
  size_t off = 0;
  auto alloc = [&](size_t bytes) -> char* {
    char* p = w + off;
    off = (off + bytes + 255) & ~(size_t)255;
    return p;
  };
  float*          pre0   = (float*)alloc(KS * 4);
  float*          lseC   = (float*)alloc(KS * 4);
  float*          nll    = (float*)alloc(N_SEQ * 4);
  float*          alphaG = (float*)alloc((size_t)N_SEQ * KS * 4);
  float*          emax   = (float*)alloc((size_t)N_SEQ * T_LEN * 4);          // 64 KB
  unsigned short* trb    = (unsigned short*)alloc((size_t)KK * EDIM * 2);     // 8.39 MB
  unsigned short* exb    = (unsigned short*)alloc((size_t)MROWS * EDIM * 2);  // 8.39 MB
  float*          emis   = (float*)alloc((size_t)N_SEQ * T_LEN * KS * 4);     // 8.39 MB
  float*          srowR  = (float*)alloc((size_t)MROWS * KS * 4);             // 8.39 MB
  // chunk region: S chunk + srowP partials; also aliases transient C
  char* region = w + off;
  size_t avail = (ws_size > off) ? (ws_size - off) : 0;
  float* C = (float*)region;                       // 16.38 MB transient

  // per chunk of Tc steps: R = Tc*64 rows; bytes = R*(16384 + 8192)
  int Tc = 2;
  for (int c = 2; c <= 64; c += 2)
    if ((size_t)c * 64 * 24576 <= avail) Tc = c;
  int Rcap = Tc * 64;
  unsigned char* S     = (unsigned char*)region;
  float*         srowP = (float*)(region + (size_t)Rcap * KK);

  hipLaunchKernelGGL(k_prep,       dim3(1),        dim3(128), 0, stream, start_w, start_b, pre0);
  hipLaunchKernelGGL(k_transcvt,   dim3(4096),     dim3(256), 0, stream, trans_w, trb);
  hipLaunchKernelGGL(k_embed,      dim3(16384),    dim3(256), 0, stream, x, embed_w, exb);
  hipLaunchKernelGGL(k_emitlogits, dim3(500, 2),   dim3(256), 0, stream, ecl, emw, C);
  hipLaunchKernelGGL(k_lsec,       dim3(128),      dim3(256), 0, stream, C, lseC);
  hipLaunchKernelGGL(k_emis,       dim3(255, 64),  dim3(128), 0, stream, x, C, lseC, emis, emax);

  int t0 = 1;
  while (t0 < T_LEN) {
    int tc = T_LEN - t0; if (tc > Tc) tc = Tc;
    int m_base = (t0 - 1) * 64;
    int gx = (tc * 64 + 127) / 128;
    hipLaunchKernelGGL(k_gemm, dim3(gx, GPART), dim3(256), 0, stream, exb, trb, S, srowP, m_base, Rcap);
    hipLaunchKernelGGL(k_comb, dim3(gx * 64),   dim3(256), 0, stream, srowP, srowR, m_base, Rcap, gx * 128);
    hipLaunchKernelGGL(k_scan, dim3(64),        dim3(64),  0, stream, S, srowR, emis, emax, pre0, alphaG, nll, t0, tc);
    t0 += tc;
  }
  hipLaunchKernelGGL(k_final, dim3(1), dim3(64), 0, stream, nll, (float*)d_out);
}

// Round 9
// 583.596 us; speedup vs baseline: 1.2814x; 1.1470x over previous
//
#include <hip/hip_runtime.h>
#include <cstdint>
#include <cstddef>

// Problem constants (fixed by reference)
#define N_SEQ 64
#define T_LEN 256
#define VOCAB 32000
#define EDIM  256
#define KS    128          // hidden states
#define KK    16384        // KS*KS
#define MROWS 16384        // padded (t,n) rows for GEMM (real: 255*64 = 16320)
#define MREAL 16320
#define GPART 16           // srow partial groups (by-split in gemm grid)

typedef short  short8  __attribute__((ext_vector_type(8)));
typedef float  floatx4 __attribute__((ext_vector_type(4)));
typedef int    intx8   __attribute__((ext_vector_type(8)));

#define LGKM_BARRIER() asm volatile("s_waitcnt lgkmcnt(0)\n\ts_barrier" ::: "memory")
#define LGKM_WAIT()    asm volatile("s_waitcnt lgkmcnt(0)" ::: "memory")

static __device__ __forceinline__ unsigned short f2bf(float f) {
  unsigned u = __float_as_uint(f);
  u += 0x7fffu + ((u >> 16) & 1u);          // RNE
  return (unsigned short)(u >> 16);
}

static __device__ __forceinline__ void gl_lds16(const void* gptr, void* lptr) {
  __builtin_amdgcn_global_load_lds(
      (const __attribute__((address_space(1))) void*)gptr,
      (__attribute__((address_space(3))) void*)lptr, 16, 0, 0);
}

// ---------------- start-distribution log_softmax -------------------------
__global__ __launch_bounds__(128) void k_prep(const float* sw, const float* sb, float* pre0) {
  __shared__ float vals[KS];
  __shared__ float MM, LS;
  int tid = threadIdx.x;
  float v = sw[tid] + sb[tid];
  vals[tid] = v;
  __syncthreads();
  if (tid == 0) { float m = vals[0]; for (int i = 1; i < KS; ++i) m = fmaxf(m, vals[i]); MM = m; }
  __syncthreads();
  float e = __expf(v - MM);
  vals[tid] = e;
  __syncthreads();
  if (tid == 0) { float s = 0.f; for (int i = 0; i < KS; ++i) s += vals[i]; LS = MM + __logf(s); }
  __syncthreads();
  pre0[tid] = v - LS;
}

// ------- trans_w fp32 -> bf16, ROW-PERMUTED row'=(j)*128+(i), k-SWIZZLED -
__global__ __launch_bounds__(256) void k_transcvt(const float* tw, unsigned short* tb) {
  int idx = blockIdx.x * 256 + threadIdx.x;          // over float4 groups
  if (idx >= (KK * EDIM) / 4) return;
  int row = idx >> 6, e4 = idx & 63;
  int rowp = ((row & 127) << 7) | (row >> 7);
  int e4s = (e4 & 0x31) | (((((e4 >> 1) & 7) ^ (rowp & 7))) << 1);
  float4 v = *(const float4*)&tw[(size_t)idx * 4];
  unsigned h0 = f2bf(v.x), h1 = f2bf(v.y), h2 = f2bf(v.z), h3 = f2bf(v.w);
  uint2 o; o.x = h0 | (h1 << 16); o.y = h2 | (h3 << 16);
  *(uint2*)&tb[(size_t)rowp * EDIM + e4s * 4] = o;
}

// ------- gather token embeddings -> bf16 rows m = t*64+n, k-SWIZZLED -----
__global__ __launch_bounds__(256) void k_embed(const int* x, const float* ew, unsigned short* exb) {
  int m = blockIdx.x, e = threadIdx.x;
  int t = m >> 6, n = m & 63;
  float v = 0.f;
  if (m < MREAL) { int tok = x[n * T_LEN + t]; v = ew[(size_t)tok * EDIM + e]; }
  int es = (e & 0xC7) | ((((e >> 3) & 7) ^ (m & 7)) << 3);
  exb[(size_t)m * EDIM + es] = f2bf(v);
}

// ---------------- emission logits C[k][v] = ecl[k] . emit_w[v] -----------
__global__ __launch_bounds__(256) void k_emitlogits(const float* ecl, const float* emw, float* C) {
  int v0 = blockIdx.x * 64, k0 = blockIdx.y * 64;
  int tid = threadIdx.x;
  __shared__ alignas(16) float At[64 * 17];
  __shared__ alignas(16) float Bt[64 * 17];
  int tx = tid & 15, ty = tid >> 4;
  int r = tid >> 2, q = tid & 3;
  float acc[4][4] = {};
  for (int d0 = 0; d0 < KS; d0 += 16) {
    float4 av = *(const float4*)&ecl[(size_t)(k0 + r) * KS + d0 + q * 4];
    float4 bv = *(const float4*)&emw[(size_t)(v0 + r) * KS + d0 + q * 4];
    __syncthreads();
    At[r * 17 + q * 4 + 0] = av.x; At[r * 17 + q * 4 + 1] = av.y;
    At[r * 17 + q * 4 + 2] = av.z; At[r * 17 + q * 4 + 3] = av.w;
    Bt[r * 17 + q * 4 + 0] = bv.x; Bt[r * 17 + q * 4 + 1] = bv.y;
    Bt[r * 17 + q * 4 + 2] = bv.z; Bt[r * 17 + q * 4 + 3] = bv.w;
    __syncthreads();
    #pragma unroll
    for (int dd = 0; dd < 16; ++dd) {
      float a[4], b[4];
      #pragma unroll
      for (int i = 0; i < 4; ++i) a[i] = At[(ty * 4 + i) * 17 + dd];
      #pragma unroll
      for (int i = 0; i < 4; ++i) b[i] = Bt[(tx * 4 + i) * 17 + dd];
      #pragma unroll
      for (int i = 0; i < 4; ++i)
        #pragma unroll
        for (int jj = 0; jj < 4; ++jj) acc[i][jj] += a[i] * b[jj];
    }
  }
  #pragma unroll
  for (int i = 0; i < 4; ++i) {
    float4 o; o.x = acc[i][0]; o.y = acc[i][1]; o.z = acc[i][2]; o.w = acc[i][3];
    *(float4*)&C[(size_t)(k0 + ty * 4 + i) * VOCAB + v0 + tx * 4] = o;
  }
}

// ---------------- per-cluster lse over vocab -----------------------------
__global__ __launch_bounds__(256) void k_lsec(const float* C, float* lseC) {
  int k = blockIdx.x, tid = threadIdx.x;
  __shared__ float sm[4], ss[4];
  const float* row = C + (size_t)k * VOCAB;
  float m = -1e30f;
  for (int v = tid; v < VOCAB; v += 256) m = fmaxf(m, row[v]);
  #pragma unroll
  for (int s = 1; s < 64; s <<= 1) m = fmaxf(m, __shfl_xor(m, s));
  if ((tid & 63) == 0) sm[tid >> 6] = m;
  __syncthreads();
  m = fmaxf(fmaxf(sm[0], sm[1]), fmaxf(sm[2], sm[3]));
  float sum = 0.f;
  for (int v = tid; v < VOCAB; v += 256) sum += __expf(row[v] - m);
  #pragma unroll
  for (int s = 1; s < 64; s <<= 1) sum += __shfl_xor(sum, s);
  if ((tid & 63) == 0) ss[tid >> 6] = sum;
  __syncthreads();
  if (tid == 0) lseC[k] = m + __logf(ss[0] + ss[1] + ss[2] + ss[3]);
}

// ------- gather emission log-probs emis[n][t][k] + per-(n,t) max ---------
__global__ __launch_bounds__(128) void k_emis(const int* x, const float* C, const float* lseC,
                                              float* emis, float* emax) {
  int t = blockIdx.x + 1;          // 1..255
  int n = blockIdx.y;
  int k = threadIdx.x;
  __shared__ float red[2];
  int w = x[n * T_LEN + t];
  float v = C[(size_t)k * VOCAB + w] - lseC[k];
  emis[(size_t)((n << 8) + t) * KS + k] = v;
  float m = v;
  #pragma unroll
  for (int s = 1; s < 64; s <<= 1) m = fmaxf(m, __shfl_xor(m, s));
  if ((k & 63) == 0) red[k >> 6] = m;
  __syncthreads();
  if (k == 0) emax[n * T_LEN + t] = fmaxf(red[0], red[1]);
}

// ---- combine srow partials -> srowR[m][i] = 1/sum (global m indexing) ---
__global__ __launch_bounds__(256) void k_comb(const float* srowP, float* srowR,
                                              int m_base, int Rcap, int rows) {
  int id = blockIdx.x * 256 + threadIdx.x;
  if (id >= rows * KS) return;
  float s = 0.f;
  #pragma unroll
  for (int g = 0; g < GPART; ++g) s += srowP[(size_t)g * Rcap * KS + id];
  srowR[(size_t)m_base * KS + id] = 1.0f / s;
}

// ---------------- scan helpers (one wave per sequence) -------------------
static __device__ __forceinline__ void scan_load_S(const unsigned char* Sbase,
                                                   int l15, int kg, intx8 (&sf)[8]) {
  #pragma unroll
  for (int q = 0; q < 8; ++q) {
    const uint4* p = (const uint4*)(Sbase + (size_t)(q * 16 + l15) * 128 + kg * 32);
    uint4 a = p[0], b = p[1];
    sf[q][0] = a.x; sf[q][1] = a.y; sf[q][2] = a.z; sf[q][3] = a.w;
    sf[q][4] = b.x; sf[q][5] = b.y; sf[q][6] = b.z; sf[q][7] = b.w;
  }
}

static __device__ __forceinline__ void scan_step(
    int t, int t0, int t1, int n, int l15, int kg, bool do_u,
    const unsigned char* Sc, const float* srowR, const float* emis, const float* emax,
    unsigned char* uL8, intx8 (&sf)[8], intx8& uf,
    float (&em)[8], float (&rs)[8], float& exR,
    float (&pre)[8], float& M) {
  const float SCALE = 4096.0f;
  const float LNS = 8.317766167f;              // ln(4096)
  floatx4 cz = {0.f, 0.f, 0.f, 0.f};
  float cv[8];
  #pragma unroll
  for (int q = 0; q < 8; ++q) {
    floatx4 d = __builtin_amdgcn_mfma_scale_f32_16x16x128_f8f6f4(
        uf, sf[q], cz, 0, 0, 0, 0x7F7F7F7F, 0, 0x7F7F7F7F);
    cv[q] = d[0];
  }
  // prefetch S(t+2) into sf (regs already consumed by the MFMAs)
  int tp = (t + 2 < t1) ? (t + 2) : (t1 - 1);
  scan_load_S(Sc + (size_t)((tp - t0) * 64 + n) * KK, l15, kg, sf);
  // alpha update for step t
  float c0 = __uint_as_float(__builtin_amdgcn_readfirstlane(__float_as_uint(cv[0])));
  float Mn = M + exR + __logf(c0) - LNS;
  #pragma unroll
  for (int q = 0; q < 8; ++q) pre[q] = M - LNS + __logf(cv[q]) + em[q];
  M = Mn;
  if (do_u) {
    #pragma unroll
    for (int q = 0; q < 8; ++q) {
      float up = __expf(pre[q] - M) * rs[q] * SCALE;
      int pk = __builtin_amdgcn_cvt_pk_fp8_f32(up, up, 0, 0);
      uL8[q * 16 + l15] = (unsigned char)(pk & 0xff);
    }
  }
  // scalar prefetch (t+2) — global loads, ride across the lgkm wait
  em[0] = emis[(size_t)((n << 8) + tp) * KS + 0 * 16 + l15];
  em[1] = emis[(size_t)((n << 8) + tp) * KS + 1 * 16 + l15];
  em[2] = emis[(size_t)((n << 8) + tp) * KS + 2 * 16 + l15];
  em[3] = emis[(size_t)((n << 8) + tp) * KS + 3 * 16 + l15];
  em[4] = emis[(size_t)((n << 8) + tp) * KS + 4 * 16 + l15];
  em[5] = emis[(size_t)((n << 8) + tp) * KS + 5 * 16 + l15];
  em[6] = emis[(size_t)((n << 8) + tp) * KS + 6 * 16 + l15];
  em[7] = emis[(size_t)((n << 8) + tp) * KS + 7 * 16 + l15];
  #pragma unroll
  for (int q = 0; q < 8; ++q) rs[q] = srowR[(size_t)(tp * 64 + n) * KS + q * 16 + l15];
  exR = emax[n * T_LEN + tp];
  if (do_u) {
    LGKM_WAIT();
    uint4 ua = *(const uint4*)&uL8[kg * 32];
    uint4 ub = *(const uint4*)&uL8[kg * 32 + 16];
    uf[0] = ua.x; uf[1] = ua.y; uf[2] = ua.z; uf[3] = ua.w;
    uf[4] = ub.x; uf[5] = ub.y; uf[6] = ub.z; uf[7] = ub.w;
  }
}

// ---- FUSED kernel: blocks [0,64) = scan of chunk c-1 (one wave each);
//      blocks [64, 64+gx*16) = GEMM of chunk c. Independent work items.
__global__ __launch_bounds__(256, 2) void k_fused(
    const unsigned short* exb, const unsigned short* trb,
    unsigned char* Sg, float* srowP, int m_base, int Rcap,
    const unsigned char* Ss, const float* srowR, const float* emis,
    const float* emax, const float* pre0, float* alphaG, float* nll,
    int t0s, int tcs) {
  __shared__ alignas(16) unsigned short As[128 * 64];
  __shared__ alignas(16) unsigned short Bs[128 * 64];
  __shared__ alignas(16) unsigned char uL8[KS];

  if (blockIdx.x < 64) {
    // ---------------- scan path (one wave; extra waves exit) -------------
    if (tcs <= 0 || threadIdx.x >= 64) return;
    int n = blockIdx.x;
    int L = threadIdx.x, l15 = L & 15, kg = L >> 4;
    const float SCALE = 4096.0f;
    int t1 = t0s + tcs;
    const float* a0 = (t0s == 1) ? pre0 : (alphaG + (size_t)n * KS);
    float pre[8];
    #pragma unroll
    for (int q = 0; q < 8; ++q) pre[q] = a0[q * 16 + l15];
    float mx = pre[0];
    #pragma unroll
    for (int q = 1; q < 8; ++q) mx = fmaxf(mx, pre[q]);
    #pragma unroll
    for (int s2 = 1; s2 < 16; s2 <<= 1) mx = fmaxf(mx, __shfl_xor(mx, s2));
    float M = mx;
    // u(t0)
    #pragma unroll
    for (int q = 0; q < 8; ++q) {
      float r0 = srowR[(size_t)((t0s - 1) * 64 + n) * KS + q * 16 + l15];
      float up = __expf(pre[q] - M) * r0 * SCALE;
      int pk = __builtin_amdgcn_cvt_pk_fp8_f32(up, up, 0, 0);
      uL8[q * 16 + l15] = (unsigned char)(pk & 0xff);
    }
    LGKM_WAIT();
    intx8 uf;
    {
      uint4 ua = *(const uint4*)&uL8[kg * 32];
      uint4 ub = *(const uint4*)&uL8[kg * 32 + 16];
      uf[0] = ua.x; uf[1] = ua.y; uf[2] = ua.z; uf[3] = ua.w;
      uf[4] = ub.x; uf[5] = ub.y; uf[6] = ub.z; uf[7] = ub.w;
    }
    intx8 sfA[8], sfB[8];
    scan_load_S(Ss + (size_t)n * KK, l15, kg, sfA);
    int tB = (t0s + 1 < t1) ? (t0s + 1) : (t1 - 1);
    scan_load_S(Ss + (size_t)((tB - t0s) * 64 + n) * KK, l15, kg, sfB);
    float emA[8], rsA[8], emB[8], rsB[8];
    #pragma unroll
    for (int q = 0; q < 8; ++q) {
      emA[q] = emis[(size_t)((n << 8) + t0s) * KS + q * 16 + l15];
      rsA[q] = srowR[(size_t)(t0s * 64 + n) * KS + q * 16 + l15];
      emB[q] = emis[(size_t)((n << 8) + tB) * KS + q * 16 + l15];
      rsB[q] = srowR[(size_t)(tB * 64 + n) * KS + q * 16 + l15];
    }
    float exA = emax[n * T_LEN + t0s];
    float exB = emax[n * T_LEN + tB];
    int t = t0s;
    for (;;) {
      scan_step(t, t0s, t1, n, l15, kg, (t + 1 < t1), Ss, srowR, emis, emax,
                uL8, sfA, uf, emA, rsA, exA, pre, M);
      ++t; if (t >= t1) break;
      scan_step(t, t0s, t1, n, l15, kg, (t + 1 < t1), Ss, srowR, emis, emax,
                uL8, sfB, uf, emB, rsB, exB, pre, M);
      ++t; if (t >= t1) break;
    }
    #pragma unroll
    for (int q = 0; q < 8; ++q) alphaG[(size_t)n * KS + q * 16 + l15] = pre[q];
    if (t1 == T_LEN) {
      float m2 = pre[0];
      #pragma unroll
      for (int q = 1; q < 8; ++q) m2 = fmaxf(m2, pre[q]);
      #pragma unroll
      for (int s2 = 1; s2 < 16; s2 <<= 1) m2 = fmaxf(m2, __shfl_xor(m2, s2));
      float e = 0.f;
      #pragma unroll
      for (int q = 0; q < 8; ++q) e += __expf(pre[q] - m2);
      #pragma unroll
      for (int s2 = 1; s2 < 16; s2 <<= 1) e += __shfl_xor(e, s2);
      if (L == 0) nll[n] = m2 + __logf(e);
    }
    return;
  }

  // ---------------- GEMM path ------------------------------------------
  int g = blockIdx.x - 64;
  int bx = g >> 4, grp = g & 15;
  int tid = threadIdx.x, wv = tid >> 6, ln = tid & 63;
  int wc = wv & 1, wm = wv >> 1;
  int m0 = m_base + bx * 128;
  int lr = ln & 15, lk = (ln >> 4) * 8;
  int lg = ln >> 4;
  floatx4 sacc[4][4] = {};
  for (int byi = 0; byi < 8; ++byi) {
    int by = grp * 8 + byi;
    int c0 = by * 128;
    floatx4 acc[4][4] = {};
    for (int k0 = 0; k0 < EDIM; k0 += 64) {
      #pragma unroll
      for (int r = 0; r < 4; ++r) {
        int chunk = (wv * 4 + r) * 64 + ln;
        int row = chunk >> 3, c8 = chunk & 7;
        gl_lds16(&exb[(size_t)(m0 + row) * EDIM + k0 + c8 * 8], &As[(wv * 4 + r) * 512]);
        gl_lds16(&trb[(size_t)(c0 + row) * EDIM + k0 + c8 * 8], &Bs[(wv * 4 + r) * 512]);
      }
      __syncthreads();                         // staging arrival (vmcnt drain)
      #pragma unroll
      for (int kk = 0; kk < 64; kk += 32) {
        int sw = ((((kk + lk) >> 3) ^ (lr & 7)) << 3);
        short8 af[4], bf[4];
        #pragma unroll
        for (int f = 0; f < 4; ++f)
          af[f] = *(const short8*)&As[(wm * 64 + f * 16 + lr) * 64 + sw];
        #pragma unroll
        for (int f = 0; f < 4; ++f)
          bf[f] = *(const short8*)&Bs[(wc * 64 + f * 16 + lr) * 64 + sw];
        #pragma unroll
        for (int fc = 0; fc < 4; ++fc)
          #pragma unroll
          for (int fm = 0; fm < 4; ++fm)
            acc[fc][fm] = __builtin_amdgcn_mfma_f32_16x16x32_bf16(bf[fc], af[fm], acc[fc][fm], 0, 0, 0);
      }
      LGKM_BARRIER();
    }
    unsigned char* Ts = (unsigned char*)As;
    #pragma unroll
    for (int fc = 0; fc < 4; ++fc) {
      #pragma unroll
      for (int fm = 0; fm < 4; ++fm) {
        floatx4 a = acc[fc][fm];
        float e0 = __expf(a[0]), e1 = __expf(a[1]), e2 = __expf(a[2]), e3 = __expf(a[3]);
        int p = __builtin_amdgcn_cvt_pk_fp8_f32(e0, e1, 0, 0);
        p = __builtin_amdgcn_cvt_pk_fp8_f32(e2, e3, p, 1);
        int mloc = wm * 64 + fm * 16 + lr;
        int cl = wc * 64 + fc * 16 + lg * 4;
        *(int*)&Ts[mloc * 128 + (cl ^ ((mloc & 7) << 4))] = p;
        sacc[fc][fm][0] += e0; sacc[fc][fm][1] += e1;
        sacc[fc][fm][2] += e2; sacc[fc][fm][3] += e3;
      }
    }
    LGKM_BARRIER();
    #pragma unroll
    for (int r = 0; r < 4; ++r) {
      int seg = r * 256 + tid;
      int mloc = seg >> 3, s = seg & 7;
      uint4 v = *(const uint4*)&Ts[mloc * 128 + ((s ^ (mloc & 7)) << 4)];
      *(uint4*)&Sg[(size_t)(bx * 128 + mloc) * KK + c0 + s * 16] = v;
    }
    LGKM_BARRIER();
  }
  #pragma unroll
  for (int fc = 0; fc < 4; ++fc) {
    #pragma unroll
    for (int fm = 0; fm < 4; ++fm) {
      int mloc = bx * 128 + wm * 64 + fm * 16 + lr;
      int i = wc * 64 + fc * 16 + lg * 4;
      *(floatx4*)&srowP[((size_t)grp * Rcap + mloc) * KS + i] = sacc[fc][fm];
    }
  }
}

// ---------------- final: out = -mean(nll) --------------------------------
__global__ __launch_bounds__(64) void k_final(const float* nll, float* out) {
  int tid = threadIdx.x;
  float v = nll[tid];
  #pragma unroll
  for (int s = 1; s < 64; s <<= 1) v += __shfl_xor(v, s);
  if (tid == 0) out[0] = -v / 64.0f;
}

extern "C" void kernel_launch(void* const* d_in, const int* in_sizes, int n_in,
                              void* d_out, int out_size, void* d_ws, size_t ws_size,
                              hipStream_t stream) {
  const int*   x       = (const int*)d_in[0];
  const float* embed_w = (const float*)d_in[1];
  const float* trans_w = (const float*)d_in[2];
  const float* start_w = (const float*)d_in[3];
  const float* start_b = (const float*)d_in[4];
  const float* ecl     = (const float*)d_in[5];
  const float* emw     = (const float*)d_in[6];

  char* w = (char*)d_ws;
  size_t off = 0;
  auto alloc = [&](size_t bytes) -> char* {
    char* p = w + off;
    off = (off + bytes + 255) & ~(size_t)255;
    return p;
  };
  float*          pre0   = (float*)alloc(KS * 4);
  float*          lseC   = (float*)alloc(KS * 4);
  float*          nll    = (float*)alloc(N_SEQ * 4);
  float*          alphaG = (float*)alloc((size_t)N_SEQ * KS * 4);
  float*          emax   = (float*)alloc((size_t)N_SEQ * T_LEN * 4);
  unsigned short* trb    = (unsigned short*)alloc((size_t)KK * EDIM * 2);
  unsigned short* exb    = (unsigned short*)alloc((size_t)MROWS * EDIM * 2);
  float*          emis   = (float*)alloc((size_t)N_SEQ * T_LEN * KS * 4);
  float*          srowR  = (float*)alloc((size_t)MROWS * KS * 4);
  // region: S double buffer + srowP; transient C aliases region start
  char* region = w + off;
  size_t avail = (ws_size > off) ? (ws_size - off) : 0;
  float* C = (float*)region;

  // per chunk: R = Tc*64 rows; need 2*R*16384 (S dbuf) + R*8192 (srowP)
  int Tc = 2;
  for (int c = 2; c <= 64; c += 2)
    if ((size_t)c * 64 * 40960 <= avail) Tc = c;
  int Rcap = Tc * 64;
  unsigned char* S0    = (unsigned char*)region;
  unsigned char* S1    = (unsigned char*)(region + (size_t)Rcap * KK);
  float*         srowP = (float*)(region + (size_t)2 * Rcap * KK);

  hipLaunchKernelGGL(k_prep,       dim3(1),        dim3(128), 0, stream, start_w, start_b, pre0);
  hipLaunchKernelGGL(k_transcvt,   dim3(4096),     dim3(256), 0, stream, trans_w, trb);
  hipLaunchKernelGGL(k_embed,      dim3(16384),    dim3(256), 0, stream, x, embed_w, exb);
  hipLaunchKernelGGL(k_emitlogits, dim3(500, 2),   dim3(256), 0, stream, ecl, emw, C);
  hipLaunchKernelGGL(k_lsec,       dim3(128),      dim3(256), 0, stream, C, lseC);
  hipLaunchKernelGGL(k_emis,       dim3(255, 64),  dim3(128), 0, stream, x, C, lseC, emis, emax);

  // chunk table
  int ct0[140], ctc[140], nc = 0;
  {
    int t0 = 1;
    while (t0 < T_LEN) {
      int tc = T_LEN - t0; if (tc > Tc) tc = Tc;
      ct0[nc] = t0; ctc[nc] = tc; ++nc; t0 += tc;
    }
  }
  // pipeline: fused_c = gemm(chunk c) + scan(chunk c-1); then comb(c)
  for (int c = 0; c <= nc; ++c) {
    bool hasG = (c < nc), hasS = (c > 0);
    int gx = 0, m_base = 0;
    if (hasG) { gx = (ctc[c] * 64 + 127) / 128; m_base = (ct0[c] - 1) * 64; }
    unsigned char* Sg = (c & 1) ? S1 : S0;
    unsigned char* Ssc = ((c - 1) & 1) ? S1 : S0;
    int t0s = hasS ? ct0[c - 1] : 0;
    int tcs = hasS ? ctc[c - 1] : 0;
    hipLaunchKernelGGL(k_fused, dim3(64 + gx * 16), dim3(256), 0, stream,
                       exb, trb, Sg, srowP, m_base, Rcap,
                       Ssc, srowR, emis, emax, pre0, alphaG, nll, t0s, tcs);
    if (hasG)
      hipLaunchKernelGGL(k_comb, dim3(gx * 64), dim3(256), 0, stream,
                         srowP, srowR, m_base, Rcap, gx * 128);
  }
  hipLaunchKernelGGL(k_final, dim3(1), dim3(64), 0, stream, nll, (float*)d_out);
}